// Round 2
// baseline (2082.673 us; speedup 1.0000x reference)
//
#include <hip/hip_runtime.h>
#include <hip/hip_bf16.h>
#include <cmath>

typedef __hip_bfloat16 bf16;
typedef __attribute__((ext_vector_type(8))) short short8;
typedef __attribute__((ext_vector_type(4))) short short4v;
typedef __attribute__((ext_vector_type(4))) float floatx4;
typedef __attribute__((ext_vector_type(4))) int intx4;

#define DMODEL 1024
#define DSTATE 16
#define DINNER 2048
#define DTRANK 64
#define NB 2
#define NT 4096
#define NM (NB * NT) /* 8192 rows */
#define GG (2 * DINNER) /* 4096 */

static __device__ __forceinline__ float bits2f(unsigned short s) {
  unsigned u = ((unsigned)s) << 16;
  float f;
  __builtin_memcpy(&f, &u, 4);
  return f;
}
static __device__ __forceinline__ short f2bits(float f) {
  bf16 h = __float2bfloat16(f);
  short s;
  __builtin_memcpy(&s, &h, 2);
  return s;
}

// -------- dtype detect: A_log[0..1] = {log1, log2}. First 4 bytes as u32:
// f32 -> 0x00000000 ; bf16 -> 0x3F310000 (nonzero). flag=1 means bf16.
__global__ void detect_k(const unsigned* __restrict__ a_log_raw, int* __restrict__ flag) {
  if (threadIdx.x == 0) *flag = (a_log_raw[0] != 0u) ? 1 : 0;
}

// -------- convert any input (f32 or bf16 per flag) to bf16 --------
__global__ void convert_k(const void* __restrict__ in, bf16* __restrict__ out, int n,
                          const int* __restrict__ flag) {
  int i = blockIdx.x * 256 + threadIdx.x;
  if (i >= n) return;
  int fl = *flag;
  out[i] = fl ? ((const bf16*)in)[i]
              : __float2bfloat16(((const float*)in)[i]);
}

// -------- transpose + convert: out[C][R] = in[R][C] --------
__global__ void transpose_k(const void* __restrict__ in, bf16* __restrict__ out,
                            int R, int C, const int* __restrict__ flag) {
  size_t idx = (size_t)blockIdx.x * 256 + threadIdx.x;
  if (idx >= (size_t)R * C) return;
  int fl = *flag;
  int c = (int)(idx / R);
  int r = (int)(idx % R);
  size_t src = (size_t)r * C + c;
  bf16 v = fl ? ((const bf16*)in)[src] : __float2bfloat16(((const float*)in)[src]);
  out[(size_t)c * R + r] = v;
}

// ---------------- rmsnorm: per-row over 1024 (reads converted bf16) --------
__global__ __launch_bounds__(256) void rmsnorm_k(const bf16* __restrict__ x,
                                                 const bf16* __restrict__ w,
                                                 bf16* __restrict__ xn) {
  int row = blockIdx.x;
  const bf16* xp = x + (size_t)row * DMODEL;
  int tid = threadIdx.x;
  short4v raw = *(const short4v*)(xp + tid * 4);
  float f[4];
#pragma unroll
  for (int k = 0; k < 4; k++) f[k] = bits2f((unsigned short)raw[k]);
  float s = f[0] * f[0] + f[1] * f[1] + f[2] * f[2] + f[3] * f[3];
#pragma unroll
  for (int o = 32; o > 0; o >>= 1) s += __shfl_down(s, o);
  __shared__ float ps[4];
  __shared__ float stot;
  if ((tid & 63) == 0) ps[tid >> 6] = s;
  __syncthreads();
  if (tid == 0) stot = ps[0] + ps[1] + ps[2] + ps[3];
  __syncthreads();
  float scale = 1.0f / sqrtf(stot * (1.0f / DMODEL) + 1e-5f);
  short4v wr = *(const short4v*)(w + tid * 4);
  short4v o;
#pragma unroll
  for (int k = 0; k < 4; k++)
    o[k] = f2bits(f[k] * scale * bits2f((unsigned short)wr[k]));
  *(short4v*)(xn + (size_t)row * DMODEL + tid * 4) = o;
}

// ---------------- GEMM: C[M,N] = A[M,K] @ Bt[N,K]^T ----------------
// 128x128 tile, BK=32, 256 thr (4 waves 2x2), mfma_f32_16x16x32_bf16.
// EPI: 0 = store bf16; 1 = store f32; 2 = softplus(v + b[n]) f32;
//      3 = v + x, store bf16 or f32 per *flag
#define LDP 40 /* padded LDS row stride in elems (80B) */
template <int EPI>
__global__ __launch_bounds__(256, 2) void gemm_bt(
    const bf16* __restrict__ A, const bf16* __restrict__ Bt, void* __restrict__ Cout,
    int M, int N, int K, const bf16* __restrict__ eb, const bf16* __restrict__ ex,
    const int* __restrict__ flag) {
  __shared__ bf16 As[128 * LDP];
  __shared__ bf16 Bs[128 * LDP];
  int tid = threadIdx.x;
  int lane = tid & 63;
  int wave = tid >> 6;
  int wm = (wave >> 1) * 64, wn = (wave & 1) * 64;
  int m0 = blockIdx.y * 128, n0 = blockIdx.x * 128;

  floatx4 acc[4][4] = {};

  int sr = tid >> 2;          // staging row 0..63
  int sc = (tid & 3) * 8;     // staging k-col in elems

  for (int k0 = 0; k0 < K; k0 += 32) {
    intx4 a0 = *(const intx4*)(A + (size_t)(m0 + sr) * K + k0 + sc);
    intx4 a1 = *(const intx4*)(A + (size_t)(m0 + sr + 64) * K + k0 + sc);
    int bn0 = n0 + sr;        if (bn0 > N - 1) bn0 = N - 1;
    int bn1 = n0 + sr + 64;   if (bn1 > N - 1) bn1 = N - 1;
    intx4 b0 = *(const intx4*)(Bt + (size_t)bn0 * K + k0 + sc);
    intx4 b1 = *(const intx4*)(Bt + (size_t)bn1 * K + k0 + sc);
    __syncthreads();
    *(intx4*)(As + sr * LDP + sc) = a0;
    *(intx4*)(As + (sr + 64) * LDP + sc) = a1;
    *(intx4*)(Bs + sr * LDP + sc) = b0;
    *(intx4*)(Bs + (sr + 64) * LDP + sc) = b1;
    __syncthreads();

    int fr = lane & 15;  // fragment row (m for A, n for B)
    int q = lane >> 4;   // k-octet
    short8 af[4], bfr[4];
#pragma unroll
    for (int i = 0; i < 4; i++) {
      af[i] = *(const short8*)(As + (wm + i * 16 + fr) * LDP + q * 8);
      bfr[i] = *(const short8*)(Bs + (wn + i * 16 + fr) * LDP + q * 8);
    }
#pragma unroll
    for (int i = 0; i < 4; i++)
#pragma unroll
      for (int j = 0; j < 4; j++)
        acc[i][j] =
            __builtin_amdgcn_mfma_f32_16x16x32_bf16(af[i], bfr[j], acc[i][j], 0, 0, 0);
  }

  int fl = (EPI == 3) ? *flag : 0;
  // epilogue: C/D layout col=lane&15, row=(lane>>4)*4+reg  [m89-verified]
  int cr = (lane >> 4) * 4;
  int cc = lane & 15;
#pragma unroll
  for (int i = 0; i < 4; i++) {
#pragma unroll
    for (int j = 0; j < 4; j++) {
      int n = n0 + wn + j * 16 + cc;
      if (n >= N) continue;
#pragma unroll
      for (int r = 0; r < 4; r++) {
        int m = m0 + wm + i * 16 + cr + r;
        float v = acc[i][j][r];
        size_t o = (size_t)m * N + n;
        if (EPI == 0) {
          ((bf16*)Cout)[o] = __float2bfloat16(v);
        } else if (EPI == 1) {
          ((float*)Cout)[o] = v;
        } else if (EPI == 2) {
          float t = v + (float)eb[n];
          ((float*)Cout)[o] = (t > 20.f) ? t : log1pf(__expf(t));
        } else {
          float v2 = v + (float)ex[o];
          if (fl) ((bf16*)Cout)[o] = __float2bfloat16(v2);
          else    ((float*)Cout)[o] = v2;
        }
      }
    }
  }
}

// ---------------- causal depthwise conv (k=4) + bias + silu ----------------
__global__ __launch_bounds__(256) void conv_silu_k(const bf16* __restrict__ xr,
                                                   const bf16* __restrict__ cw,
                                                   const bf16* __restrict__ cb,
                                                   bf16* __restrict__ u) {
  size_t idx = (size_t)blockIdx.x * 256 + threadIdx.x;  // over NM*DINNER
  int d = (int)(idx & (DINNER - 1));
  size_t m = idx >> 11;
  int t = (int)(m & (NT - 1));
  float acc = (float)cb[d];
#pragma unroll
  for (int j = 0; j < 4; j++) {
    int tt = t - 3 + j;
    if (tt >= 0)
      acc += (float)cw[d * 4 + j] * (float)xr[(m - 3 + j) * GG + d];
  }
  float s = acc / (1.f + __expf(-acc));
  u[idx] = __float2bfloat16(s);
}

// ---------------- dt slice -> bf16 ----------------
__global__ void dtcast_k(const float* __restrict__ xdbc, bf16* __restrict__ dtb) {
  size_t idx = (size_t)blockIdx.x * 256 + threadIdx.x;  // NM*64
  size_t m = idx >> 6;
  int r = (int)(idx & 63);
  dtb[idx] = __float2bfloat16(xdbc[m * 96 + r]);
}

// ---------------- selective scan: 4 lanes per channel, 4 states each -------
__global__ __launch_bounds__(256) void scan_k(
    const float* __restrict__ delta, const bf16* __restrict__ u,
    const float* __restrict__ xdbc, const bf16* __restrict__ xr,
    const bf16* __restrict__ A_log, const bf16* __restrict__ Dp,
    bf16* __restrict__ y) {
  int tid = threadIdx.x;
  int b = blockIdx.x >> 5;                 // 32 blocks per batch
  int d = ((blockIdx.x & 31) << 6) + (tid >> 2);
  int n0 = (tid & 3) * 4;
  float Av[4], h[4] = {0.f, 0.f, 0.f, 0.f};
#pragma unroll
  for (int k = 0; k < 4; k++) Av[k] = -__expf((float)A_log[d * DSTATE + n0 + k]);
  float Dd = (float)Dp[d];
  size_t base = (size_t)b * NT;

  // prefetch t=0
  size_t m = base;
  float dl = delta[m * DINNER + d];
  float uu = (float)u[m * DINNER + d];
  floatx4 Bv = *(const floatx4*)(xdbc + m * 96 + 64 + n0);
  floatx4 Cv = *(const floatx4*)(xdbc + m * 96 + 80 + n0);
  float rs = (float)xr[m * GG + DINNER + d];

  for (int t = 0; t < NT; t++) {
    float dl_n = 0.f, uu_n = 0.f, rs_n = 0.f;
    floatx4 Bv_n = {}, Cv_n = {};
    if (t + 1 < NT) {
      size_t m2 = base + t + 1;
      dl_n = delta[m2 * DINNER + d];
      uu_n = (float)u[m2 * DINNER + d];
      Bv_n = *(const floatx4*)(xdbc + m2 * 96 + 64 + n0);
      Cv_n = *(const floatx4*)(xdbc + m2 * 96 + 80 + n0);
      rs_n = (float)xr[m2 * GG + DINNER + d];
    }
    float du = dl * uu;
    float ys = 0.f;
#pragma unroll
    for (int k = 0; k < 4; k++) {
      float dA = __expf(dl * Av[k]);
      h[k] = fmaf(dA, h[k], du * Bv[k]);
      ys = fmaf(h[k], Cv[k], ys);
    }
    ys += __shfl_xor(ys, 1);
    ys += __shfl_xor(ys, 2);
    if ((tid & 3) == 0) {
      size_t mm = base + t;
      float sig = 1.f / (1.f + __expf(-rs));
      y[mm * DINNER + d] = __float2bfloat16((ys + uu * Dd) * (rs * sig));
    }
    dl = dl_n; uu = uu_n; Bv = Bv_n; Cv = Cv_n; rs = rs_n;
  }
}

// ---------------- launch ----------------
extern "C" void kernel_launch(void* const* d_in, const int* in_sizes, int n_in,
                              void* d_out, int out_size, void* d_ws, size_t ws_size,
                              hipStream_t stream) {
  const void* x_raw = d_in[0];
  const void* norm_w_raw = d_in[1];
  const void* w_in_raw = d_in[2];
  const void* conv_w_raw = d_in[3];
  const void* conv_b_raw = d_in[4];
  const void* w_x_raw = d_in[5];
  const void* w_dt_raw = d_in[6];
  const void* b_dt_raw = d_in[7];
  const void* A_log_raw = d_in[8];
  const void* Dp_raw = d_in[9];
  const void* w_out_raw = d_in[10];

  char* ws = (char*)d_ws;
  size_t off = 0;
  auto alloc = [&](size_t bytes) {
    size_t o = off;
    off += (bytes + 255) & ~(size_t)255;
    return o;
  };
  int* flag = (int*)(ws + alloc(256));
  bf16* xb = (bf16*)(ws + alloc((size_t)NM * DMODEL * 2));
  bf16* nwb = (bf16*)(ws + alloc((size_t)DMODEL * 2));
  bf16* cwb = (bf16*)(ws + alloc((size_t)DINNER * 4 * 2));
  bf16* cbb = (bf16*)(ws + alloc((size_t)DINNER * 2));
  bf16* bdtb = (bf16*)(ws + alloc((size_t)DINNER * 2));
  bf16* alogb = (bf16*)(ws + alloc((size_t)DINNER * DSTATE * 2));
  bf16* Db = (bf16*)(ws + alloc((size_t)DINNER * 2));
  bf16* xn = (bf16*)(ws + alloc((size_t)NM * DMODEL * 2));
  bf16* xr = (bf16*)(ws + alloc((size_t)NM * GG * 2));
  bf16* u = (bf16*)(ws + alloc((size_t)NM * DINNER * 2));
  float* xdbc = (float*)(ws + alloc((size_t)NM * 96 * 4));
  bf16* dtb = (bf16*)(ws + alloc((size_t)NM * 64 * 2));
  float* delta = (float*)(ws + alloc((size_t)NM * DINNER * 4));
  bf16* yb = (bf16*)(ws + alloc((size_t)NM * DINNER * 2));
  bf16* w_inT = (bf16*)(ws + alloc((size_t)DMODEL * GG * 2));
  bf16* w_xT = (bf16*)(ws + alloc((size_t)DINNER * 96 * 2));
  bf16* w_dtT = (bf16*)(ws + alloc((size_t)DTRANK * DINNER * 2));
  bf16* w_outT = (bf16*)(ws + alloc((size_t)DINNER * DMODEL * 2));

  // dtype detect
  detect_k<<<1, 64, 0, stream>>>((const unsigned*)A_log_raw, flag);

  // input normalization to bf16
  convert_k<<<(NM * DMODEL + 255) / 256, 256, 0, stream>>>(x_raw, xb, NM * DMODEL, flag);
  convert_k<<<(DMODEL + 255) / 256, 256, 0, stream>>>(norm_w_raw, nwb, DMODEL, flag);
  convert_k<<<(DINNER * 4 + 255) / 256, 256, 0, stream>>>(conv_w_raw, cwb, DINNER * 4, flag);
  convert_k<<<(DINNER + 255) / 256, 256, 0, stream>>>(conv_b_raw, cbb, DINNER, flag);
  convert_k<<<(DINNER + 255) / 256, 256, 0, stream>>>(b_dt_raw, bdtb, DINNER, flag);
  convert_k<<<(DINNER * DSTATE + 255) / 256, 256, 0, stream>>>(A_log_raw, alogb, DINNER * DSTATE, flag);
  convert_k<<<(DINNER + 255) / 256, 256, 0, stream>>>(Dp_raw, Db, DINNER, flag);

  // weight transposes (to [N][K] k-contiguous bf16)
  transpose_k<<<(DMODEL * GG + 255) / 256, 256, 0, stream>>>(w_in_raw, w_inT, DMODEL, GG, flag);
  transpose_k<<<(DINNER * 96 + 255) / 256, 256, 0, stream>>>(w_x_raw, w_xT, DINNER, 96, flag);
  transpose_k<<<(DTRANK * DINNER + 255) / 256, 256, 0, stream>>>(w_dt_raw, w_dtT, DTRANK, DINNER, flag);
  transpose_k<<<(DINNER * DMODEL + 255) / 256, 256, 0, stream>>>(w_out_raw, w_outT, DINNER, DMODEL, flag);

  // rmsnorm
  rmsnorm_k<<<NM, 256, 0, stream>>>(xb, nwb, xn);

  // xr = xn @ w_in   (M=8192, N=4096, K=1024)
  gemm_bt<0><<<dim3(GG / 128, NM / 128), 256, 0, stream>>>(xn, w_inT, xr, NM, GG,
                                                           DMODEL, nullptr, nullptr, flag);
  // conv + silu -> u
  conv_silu_k<<<(size_t)NM * DINNER / 256, 256, 0, stream>>>(xr, cwb, cbb, u);

  // xdbc = u @ w_x   (N=96, masked in a single 128-col block)
  gemm_bt<1><<<dim3(1, NM / 128), 256, 0, stream>>>(u, w_xT, xdbc, NM, 96, DINNER,
                                                    nullptr, nullptr, flag);
  // dt -> bf16
  dtcast_k<<<(size_t)NM * 64 / 256, 256, 0, stream>>>(xdbc, dtb);

  // delta = softplus(dt @ w_dt + b_dt)  (M=8192, N=2048, K=64)
  gemm_bt<2><<<dim3(DINNER / 128, NM / 128), 256, 0, stream>>>(dtb, w_dtT, delta, NM,
                                                               DINNER, DTRANK, bdtb,
                                                               nullptr, flag);
  // selective scan + gating -> yb
  scan_k<<<NB * (DINNER / 64), 256, 0, stream>>>(delta, u, xdbc, xr, alogb, Db, yb);

  // out = x + yb @ w_out  (M=8192, N=1024, K=2048)
  gemm_bt<3><<<dim3(DMODEL / 128, NM / 128), 256, 0, stream>>>(
      yb, w_outT, d_out, NM, DMODEL, DINNER, nullptr, xb, flag);
}

// Round 4
// 690.717 us; speedup vs baseline: 3.0152x; 3.0152x over previous
//
#include <hip/hip_runtime.h>
#include <hip/hip_bf16.h>
#include <cmath>

typedef __hip_bfloat16 bf16;
typedef __attribute__((ext_vector_type(8))) short short8;
typedef __attribute__((ext_vector_type(4))) short short4v;
typedef __attribute__((ext_vector_type(4))) float floatx4;
typedef __attribute__((ext_vector_type(4))) int intx4;

#define DMODEL 1024
#define DSTATE 16
#define DINNER 2048
#define DTRANK 64
#define NB 2
#define NT 4096
#define NM (NB * NT) /* 8192 rows */
#define GG (2 * DINNER) /* 4096 */
#define CL 128          /* scan chunk length */
#define NC (NT / CL)    /* 32 chunks per batch */

static __device__ __forceinline__ float bits2f(unsigned short s) {
  unsigned u = ((unsigned)s) << 16;
  float f;
  __builtin_memcpy(&f, &u, 4);
  return f;
}
static __device__ __forceinline__ short f2bits(float f) {
  bf16 h = __float2bfloat16(f);
  short s;
  __builtin_memcpy(&s, &h, 2);
  return s;
}

// -------- dtype detect: A_log[0] = log(1). As u32: f32 -> 0, bf16 -> nonzero.
__global__ void detect_k(const unsigned* __restrict__ a_log_raw, int* __restrict__ flag) {
  if (threadIdx.x == 0) *flag = (a_log_raw[0] != 0u) ? 1 : 0;
}

// -------- convert any input (f32 or bf16 per flag) to bf16 --------
__global__ void convert_k(const void* __restrict__ in, bf16* __restrict__ out, int n,
                          const int* __restrict__ flag) {
  int i = blockIdx.x * 256 + threadIdx.x;
  if (i >= n) return;
  int fl = *flag;
  out[i] = fl ? ((const bf16*)in)[i]
              : __float2bfloat16(((const float*)in)[i]);
}

// -------- transpose + convert: out[C][R] = in[R][C] --------
__global__ void transpose_k(const void* __restrict__ in, bf16* __restrict__ out,
                            int R, int C, const int* __restrict__ flag) {
  size_t idx = (size_t)blockIdx.x * 256 + threadIdx.x;
  if (idx >= (size_t)R * C) return;
  int fl = *flag;
  int c = (int)(idx / R);
  int r = (int)(idx % R);
  size_t src = (size_t)r * C + c;
  bf16 v = fl ? ((const bf16*)in)[src] : __float2bfloat16(((const float*)in)[src]);
  out[(size_t)c * R + r] = v;
}

// ---------------- rmsnorm: per-row over 1024 ----------------
__global__ __launch_bounds__(256) void rmsnorm_k(const bf16* __restrict__ x,
                                                 const bf16* __restrict__ w,
                                                 bf16* __restrict__ xn) {
  int row = blockIdx.x;
  const bf16* xp = x + (size_t)row * DMODEL;
  int tid = threadIdx.x;
  short4v raw = *(const short4v*)(xp + tid * 4);
  float f[4];
#pragma unroll
  for (int k = 0; k < 4; k++) f[k] = bits2f((unsigned short)raw[k]);
  float s = f[0] * f[0] + f[1] * f[1] + f[2] * f[2] + f[3] * f[3];
#pragma unroll
  for (int o = 32; o > 0; o >>= 1) s += __shfl_down(s, o);
  __shared__ float ps[4];
  __shared__ float stot;
  if ((tid & 63) == 0) ps[tid >> 6] = s;
  __syncthreads();
  if (tid == 0) stot = ps[0] + ps[1] + ps[2] + ps[3];
  __syncthreads();
  float scale = 1.0f / sqrtf(stot * (1.0f / DMODEL) + 1e-5f);
  short4v wr = *(const short4v*)(w + tid * 4);
  short4v o;
#pragma unroll
  for (int k = 0; k < 4; k++)
    o[k] = f2bits(f[k] * scale * bits2f((unsigned short)wr[k]));
  *(short4v*)(xn + (size_t)row * DMODEL + tid * 4) = o;
}

// ---------------- GEMM: C[M,N] = A[M,K] @ Bt[N,K]^T ----------------
#define LDP 40
template <int EPI>
__global__ __launch_bounds__(256, 2) void gemm_bt(
    const bf16* __restrict__ A, const bf16* __restrict__ Bt, void* __restrict__ Cout,
    int M, int N, int K, const bf16* __restrict__ eb, const bf16* __restrict__ ex,
    const int* __restrict__ flag) {
  __shared__ bf16 As[128 * LDP];
  __shared__ bf16 Bs[128 * LDP];
  int tid = threadIdx.x;
  int lane = tid & 63;
  int wave = tid >> 6;
  int wm = (wave >> 1) * 64, wn = (wave & 1) * 64;
  int m0 = blockIdx.y * 128, n0 = blockIdx.x * 128;

  floatx4 acc[4][4] = {};

  int sr = tid >> 2;
  int sc = (tid & 3) * 8;

  for (int k0 = 0; k0 < K; k0 += 32) {
    intx4 a0 = *(const intx4*)(A + (size_t)(m0 + sr) * K + k0 + sc);
    intx4 a1 = *(const intx4*)(A + (size_t)(m0 + sr + 64) * K + k0 + sc);
    int bn0 = n0 + sr;        if (bn0 > N - 1) bn0 = N - 1;
    int bn1 = n0 + sr + 64;   if (bn1 > N - 1) bn1 = N - 1;
    intx4 b0 = *(const intx4*)(Bt + (size_t)bn0 * K + k0 + sc);
    intx4 b1 = *(const intx4*)(Bt + (size_t)bn1 * K + k0 + sc);
    __syncthreads();
    *(intx4*)(As + sr * LDP + sc) = a0;
    *(intx4*)(As + (sr + 64) * LDP + sc) = a1;
    *(intx4*)(Bs + sr * LDP + sc) = b0;
    *(intx4*)(Bs + (sr + 64) * LDP + sc) = b1;
    __syncthreads();

    int fr = lane & 15;
    int q = lane >> 4;
    short8 af[4], bfr[4];
#pragma unroll
    for (int i = 0; i < 4; i++) {
      af[i] = *(const short8*)(As + (wm + i * 16 + fr) * LDP + q * 8);
      bfr[i] = *(const short8*)(Bs + (wn + i * 16 + fr) * LDP + q * 8);
    }
#pragma unroll
    for (int i = 0; i < 4; i++)
#pragma unroll
      for (int j = 0; j < 4; j++)
        acc[i][j] =
            __builtin_amdgcn_mfma_f32_16x16x32_bf16(af[i], bfr[j], acc[i][j], 0, 0, 0);
  }

  int fl = (EPI == 3) ? *flag : 0;
  int cr = (lane >> 4) * 4;
  int cc = lane & 15;
#pragma unroll
  for (int i = 0; i < 4; i++) {
#pragma unroll
    for (int j = 0; j < 4; j++) {
      int n = n0 + wn + j * 16 + cc;
      if (n >= N) continue;
#pragma unroll
      for (int r = 0; r < 4; r++) {
        int m = m0 + wm + i * 16 + cr + r;
        float v = acc[i][j][r];
        size_t o = (size_t)m * N + n;
        if (EPI == 0) {
          ((bf16*)Cout)[o] = __float2bfloat16(v);
        } else if (EPI == 1) {
          ((float*)Cout)[o] = v;
        } else if (EPI == 2) {
          float t = v + (float)eb[n];
          ((float*)Cout)[o] = (t > 20.f) ? t : log1pf(__expf(t));
        } else {
          float v2 = v + (float)ex[o];
          if (fl) ((bf16*)Cout)[o] = __float2bfloat16(v2);
          else    ((float*)Cout)[o] = v2;
        }
      }
    }
  }
}

// ---------------- causal depthwise conv (k=4) + bias + silu ----------------
__global__ __launch_bounds__(256) void conv_silu_k(const bf16* __restrict__ xr,
                                                   const bf16* __restrict__ cw,
                                                   const bf16* __restrict__ cb,
                                                   bf16* __restrict__ u) {
  size_t idx = (size_t)blockIdx.x * 256 + threadIdx.x;
  int d = (int)(idx & (DINNER - 1));
  size_t m = idx >> 11;
  int t = (int)(m & (NT - 1));
  float acc = (float)cb[d];
#pragma unroll
  for (int j = 0; j < 4; j++) {
    int tt = t - 3 + j;
    if (tt >= 0)
      acc += (float)cw[d * 4 + j] * (float)xr[(m - 3 + j) * GG + d];
  }
  float s = acc / (1.f + __expf(-acc));
  u[idx] = __float2bfloat16(s);
}

// ---------------- dt slice -> bf16 ----------------
__global__ void dtcast_k(const float* __restrict__ xdbc, bf16* __restrict__ dtb) {
  size_t idx = (size_t)blockIdx.x * 256 + threadIdx.x;
  size_t m = idx >> 6;
  int r = (int)(idx & 63);
  dtb[idx] = __float2bfloat16(xdbc[m * 96 + r]);
}

// ===================== chunked parallel scan =====================
// thread layout (all passes): d = dblk*64 + (tid>>2); lane quad (tid&3) holds
// states n0..n0+3, n0=(tid&3)*4.  chunkP/S/H layout: [b][chunk][d][n] f32.

// pass 1: local scan with h=0 over chunk; emit P=prod(dA), S=local final h
__global__ __launch_bounds__(256) void scan1_k(
    const float* __restrict__ delta, const bf16* __restrict__ u,
    const float* __restrict__ xdbc, const bf16* __restrict__ A_log,
    float* __restrict__ chunkP, float* __restrict__ chunkS) {
  int tid = threadIdx.x;
  int bc = blockIdx.x;
  int dblk = bc & 31;
  int chunk = (bc >> 5) & (NC - 1);
  int b = bc >> 10;
  int d = (dblk << 6) + (tid >> 2);
  int n0 = (tid & 3) * 4;
  float Av[4], h[4] = {}, P[4] = {1.f, 1.f, 1.f, 1.f};
#pragma unroll
  for (int k = 0; k < 4; k++) Av[k] = -__expf((float)A_log[d * DSTATE + n0 + k]);
  size_t base = (size_t)b * NT + (size_t)chunk * CL;

  float dl = delta[base * DINNER + d];
  float uu = (float)u[base * DINNER + d];
  floatx4 Bv = *(const floatx4*)(xdbc + base * 96 + 64 + n0);

  for (int t = 0; t < CL; t++) {
    float dl_n = 0.f, uu_n = 0.f;
    floatx4 Bv_n = {};
    if (t + 1 < CL) {
      size_t m2 = base + t + 1;
      dl_n = delta[m2 * DINNER + d];
      uu_n = (float)u[m2 * DINNER + d];
      Bv_n = *(const floatx4*)(xdbc + m2 * 96 + 64 + n0);
    }
    float du = dl * uu;
#pragma unroll
    for (int k = 0; k < 4; k++) {
      float dA = __expf(dl * Av[k]);
      h[k] = fmaf(dA, h[k], du * Bv[k]);
      P[k] *= dA;
    }
    dl = dl_n; uu = uu_n; Bv = Bv_n;
  }
  size_t o = (((size_t)b * NC + chunk) * DINNER + d) * DSTATE + n0;
  floatx4 Pv = {P[0], P[1], P[2], P[3]};
  floatx4 Sv = {h[0], h[1], h[2], h[3]};
  *(floatx4*)(chunkP + o) = Pv;
  *(floatx4*)(chunkS + o) = Sv;
}

// pass 2: sequential over chunks: emit carry-in H_c; H_{c+1} = P_c H_c + S_c
__global__ __launch_bounds__(256) void scan2_k(
    const float* __restrict__ chunkP, const float* __restrict__ chunkS,
    float* __restrict__ chunkH) {
  int tid = threadIdx.x;
  int bc = blockIdx.x;
  int dblk = bc & 31;
  int b = bc >> 5;
  int d = (dblk << 6) + (tid >> 2);
  int n0 = (tid & 3) * 4;
  floatx4 h = {};
  size_t o0 = ((size_t)b * NC * DINNER + d) * DSTATE + n0;
  floatx4 P = *(const floatx4*)(chunkP + o0);
  floatx4 S = *(const floatx4*)(chunkS + o0);
  for (int c = 0; c < NC; c++) {
    floatx4 Pn = {}, Sn = {};
    if (c + 1 < NC) {
      size_t o = o0 + (size_t)(c + 1) * DINNER * DSTATE;
      Pn = *(const floatx4*)(chunkP + o);
      Sn = *(const floatx4*)(chunkS + o);
    }
    size_t o = o0 + (size_t)c * DINNER * DSTATE;
    *(floatx4*)(chunkH + o) = h;
#pragma unroll
    for (int k = 0; k < 4; k++) h[k] = fmaf(P[k], h[k], S[k]);
    P = Pn; S = Sn;
  }
}

// pass 3: replay chunk from carry-in H, produce gated y
__global__ __launch_bounds__(256) void scan3_k(
    const float* __restrict__ delta, const bf16* __restrict__ u,
    const float* __restrict__ xdbc, const bf16* __restrict__ xr,
    const bf16* __restrict__ A_log, const bf16* __restrict__ Dp,
    const float* __restrict__ chunkH, bf16* __restrict__ y) {
  int tid = threadIdx.x;
  int bc = blockIdx.x;
  int dblk = bc & 31;
  int chunk = (bc >> 5) & (NC - 1);
  int b = bc >> 10;
  int d = (dblk << 6) + (tid >> 2);
  int n0 = (tid & 3) * 4;
  float Av[4], h[4];
#pragma unroll
  for (int k = 0; k < 4; k++) Av[k] = -__expf((float)A_log[d * DSTATE + n0 + k]);
  {
    size_t o = (((size_t)b * NC + chunk) * DINNER + d) * DSTATE + n0;
    floatx4 H = *(const floatx4*)(chunkH + o);
#pragma unroll
    for (int k = 0; k < 4; k++) h[k] = H[k];
  }
  float Dd = (float)Dp[d];
  size_t base = (size_t)b * NT + (size_t)chunk * CL;

  float dl = delta[base * DINNER + d];
  float uu = (float)u[base * DINNER + d];
  floatx4 Bv = *(const floatx4*)(xdbc + base * 96 + 64 + n0);
  floatx4 Cv = *(const floatx4*)(xdbc + base * 96 + 80 + n0);
  float rs = (float)xr[base * GG + DINNER + d];

  for (int t = 0; t < CL; t++) {
    float dl_n = 0.f, uu_n = 0.f, rs_n = 0.f;
    floatx4 Bv_n = {}, Cv_n = {};
    if (t + 1 < CL) {
      size_t m2 = base + t + 1;
      dl_n = delta[m2 * DINNER + d];
      uu_n = (float)u[m2 * DINNER + d];
      Bv_n = *(const floatx4*)(xdbc + m2 * 96 + 64 + n0);
      Cv_n = *(const floatx4*)(xdbc + m2 * 96 + 80 + n0);
      rs_n = (float)xr[m2 * GG + DINNER + d];
    }
    float du = dl * uu;
    float ys = 0.f;
#pragma unroll
    for (int k = 0; k < 4; k++) {
      float dA = __expf(dl * Av[k]);
      h[k] = fmaf(dA, h[k], du * Bv[k]);
      ys = fmaf(h[k], Cv[k], ys);
    }
    ys += __shfl_xor(ys, 1);
    ys += __shfl_xor(ys, 2);
    if ((tid & 3) == 0) {
      size_t mm = base + t;
      float sig = 1.f / (1.f + __expf(-rs));
      y[mm * DINNER + d] = __float2bfloat16((ys + uu * Dd) * (rs * sig));
    }
    dl = dl_n; uu = uu_n; Bv = Bv_n; Cv = Cv_n; rs = rs_n;
  }
}

// ---------------- launch ----------------
extern "C" void kernel_launch(void* const* d_in, const int* in_sizes, int n_in,
                              void* d_out, int out_size, void* d_ws, size_t ws_size,
                              hipStream_t stream) {
  const void* x_raw = d_in[0];
  const void* norm_w_raw = d_in[1];
  const void* w_in_raw = d_in[2];
  const void* conv_w_raw = d_in[3];
  const void* conv_b_raw = d_in[4];
  const void* w_x_raw = d_in[5];
  const void* w_dt_raw = d_in[6];
  const void* b_dt_raw = d_in[7];
  const void* A_log_raw = d_in[8];
  const void* Dp_raw = d_in[9];
  const void* w_out_raw = d_in[10];

  char* ws = (char*)d_ws;
  size_t off = 0;
  auto alloc = [&](size_t bytes) {
    size_t o = off;
    off += (bytes + 255) & ~(size_t)255;
    return o;
  };
  int* flag = (int*)(ws + alloc(256));
  bf16* xb = (bf16*)(ws + alloc((size_t)NM * DMODEL * 2));
  bf16* nwb = (bf16*)(ws + alloc((size_t)DMODEL * 2));
  bf16* cwb = (bf16*)(ws + alloc((size_t)DINNER * 4 * 2));
  bf16* cbb = (bf16*)(ws + alloc((size_t)DINNER * 2));
  bf16* bdtb = (bf16*)(ws + alloc((size_t)DINNER * 2));
  bf16* alogb = (bf16*)(ws + alloc((size_t)DINNER * DSTATE * 2));
  bf16* Db = (bf16*)(ws + alloc((size_t)DINNER * 2));
  bf16* xn = (bf16*)(ws + alloc((size_t)NM * DMODEL * 2));
  bf16* xr = (bf16*)(ws + alloc((size_t)NM * GG * 2));
  bf16* u = (bf16*)(ws + alloc((size_t)NM * DINNER * 2));
  float* xdbc = (float*)(ws + alloc((size_t)NM * 96 * 4));
  bf16* dtb = (bf16*)(ws + alloc((size_t)NM * 64 * 2));
  float* delta = (float*)(ws + alloc((size_t)NM * DINNER * 4));
  bf16* yb = (bf16*)(ws + alloc((size_t)NM * DINNER * 2));
  bf16* w_inT = (bf16*)(ws + alloc((size_t)DMODEL * GG * 2));
  bf16* w_xT = (bf16*)(ws + alloc((size_t)DINNER * 96 * 2));
  bf16* w_dtT = (bf16*)(ws + alloc((size_t)DTRANK * DINNER * 2));
  bf16* w_outT = (bf16*)(ws + alloc((size_t)DINNER * DMODEL * 2));

  // Chunk buffers ALIAS dead regions (no net workspace growth — round-3 OOM fix):
  //   xn    (16,777,216 B, dead after gemm<0>) -> chunkP | chunkS (2 x 8,388,608 B)
  //   w_inT ( 8,388,608 B, dead after gemm<0>) -> chunkH     (exact fit)
  float* chunkP = (float*)xn;
  float* chunkS = (float*)((char*)xn + (size_t)NB * NC * DINNER * DSTATE * 4);
  float* chunkH = (float*)w_inT;

  detect_k<<<1, 64, 0, stream>>>((const unsigned*)A_log_raw, flag);

  convert_k<<<(NM * DMODEL + 255) / 256, 256, 0, stream>>>(x_raw, xb, NM * DMODEL, flag);
  convert_k<<<(DMODEL + 255) / 256, 256, 0, stream>>>(norm_w_raw, nwb, DMODEL, flag);
  convert_k<<<(DINNER * 4 + 255) / 256, 256, 0, stream>>>(conv_w_raw, cwb, DINNER * 4, flag);
  convert_k<<<(DINNER + 255) / 256, 256, 0, stream>>>(conv_b_raw, cbb, DINNER, flag);
  convert_k<<<(DINNER + 255) / 256, 256, 0, stream>>>(b_dt_raw, bdtb, DINNER, flag);
  convert_k<<<(DINNER * DSTATE + 255) / 256, 256, 0, stream>>>(A_log_raw, alogb, DINNER * DSTATE, flag);
  convert_k<<<(DINNER + 255) / 256, 256, 0, stream>>>(Dp_raw, Db, DINNER, flag);

  transpose_k<<<(DMODEL * GG + 255) / 256, 256, 0, stream>>>(w_in_raw, w_inT, DMODEL, GG, flag);
  transpose_k<<<(DINNER * 96 + 255) / 256, 256, 0, stream>>>(w_x_raw, w_xT, DINNER, 96, flag);
  transpose_k<<<(DTRANK * DINNER + 255) / 256, 256, 0, stream>>>(w_dt_raw, w_dtT, DTRANK, DINNER, flag);
  transpose_k<<<(DINNER * DMODEL + 255) / 256, 256, 0, stream>>>(w_out_raw, w_outT, DINNER, DMODEL, flag);

  rmsnorm_k<<<NM, 256, 0, stream>>>(xb, nwb, xn);

  gemm_bt<0><<<dim3(GG / 128, NM / 128), 256, 0, stream>>>(xn, w_inT, xr, NM, GG,
                                                           DMODEL, nullptr, nullptr, flag);
  // xn and w_inT are dead from here on (aliased by chunkP/S/H below)
  conv_silu_k<<<(size_t)NM * DINNER / 256, 256, 0, stream>>>(xr, cwb, cbb, u);

  gemm_bt<1><<<dim3(1, NM / 128), 256, 0, stream>>>(u, w_xT, xdbc, NM, 96, DINNER,
                                                    nullptr, nullptr, flag);
  dtcast_k<<<(size_t)NM * 64 / 256, 256, 0, stream>>>(xdbc, dtb);

  gemm_bt<2><<<dim3(DINNER / 128, NM / 128), 256, 0, stream>>>(dtb, w_dtT, delta, NM,
                                                               DINNER, DTRANK, bdtb,
                                                               nullptr, flag);

  // chunked parallel scan
  scan1_k<<<NB * NC * 32, 256, 0, stream>>>(delta, u, xdbc, alogb, chunkP, chunkS);
  scan2_k<<<NB * 32, 256, 0, stream>>>(chunkP, chunkS, chunkH);
  scan3_k<<<NB * NC * 32, 256, 0, stream>>>(delta, u, xdbc, xr, alogb, Db, chunkH, yb);

  gemm_bt<3><<<dim3(DMODEL / 128, NM / 128), 256, 0, stream>>>(
      yb, w_outT, d_out, NM, DMODEL, DINNER, nullptr, xb, flag);
}

// Round 5
// 629.288 us; speedup vs baseline: 3.3096x; 1.0976x over previous
//
#include <hip/hip_runtime.h>
#include <hip/hip_bf16.h>
#include <cmath>

typedef __hip_bfloat16 bf16;
typedef __attribute__((ext_vector_type(8))) short short8;
typedef __attribute__((ext_vector_type(4))) short short4v;
typedef __attribute__((ext_vector_type(4))) float floatx4;
typedef __attribute__((ext_vector_type(4))) int intx4;

#define DMODEL 1024
#define DSTATE 16
#define DINNER 2048
#define DTRANK 64
#define NB 2
#define NT 4096
#define NM (NB * NT) /* 8192 rows */
#define GG (2 * DINNER) /* 4096 */
#define CL 128          /* scan chunk length */
#define NC (NT / CL)    /* 32 chunks per batch */

typedef __attribute__((address_space(1))) const void gvoid;
typedef __attribute__((address_space(3))) void lvoid;
static __device__ __forceinline__ void gl_lds16(const bf16* g, bf16* l) {
  // async global->LDS, 16B/lane; LDS dest = wave-uniform base + lane*16 [m97/m104]
  __builtin_amdgcn_global_load_lds((gvoid*)g, (lvoid*)l, 16, 0, 0);
}

static __device__ __forceinline__ float bits2f(unsigned short s) {
  unsigned u = ((unsigned)s) << 16;
  float f;
  __builtin_memcpy(&f, &u, 4);
  return f;
}
static __device__ __forceinline__ short f2bits(float f) {
  bf16 h = __float2bfloat16(f);
  short s;
  __builtin_memcpy(&s, &h, 2);
  return s;
}

// -------- dtype detect: A_log[0] = log(1). As u32: f32 -> 0, bf16 -> nonzero.
__global__ void detect_k(const unsigned* __restrict__ a_log_raw, int* __restrict__ flag) {
  if (threadIdx.x == 0) *flag = (a_log_raw[0] != 0u) ? 1 : 0;
}

// -------- convert any input (f32 or bf16 per flag) to bf16, 4 elems/thread ----
__global__ void convert_k(const void* __restrict__ in, bf16* __restrict__ out, int n,
                          const int* __restrict__ flag) {
  int i = (blockIdx.x * 256 + threadIdx.x) * 4;
  if (i + 3 >= n) {
    int fl = *flag;
    for (int k = 0; k < 4 && i + k < n; k++)
      out[i + k] = fl ? ((const bf16*)in)[i + k]
                      : __float2bfloat16(((const float*)in)[i + k]);
    return;
  }
  int fl = *flag;
  short4v o;
  if (fl) {
    o = *(const short4v*)((const bf16*)in + i);
  } else {
    floatx4 f = *(const floatx4*)((const float*)in + i);
#pragma unroll
    for (int k = 0; k < 4; k++) o[k] = f2bits(f[k]);
  }
  *(short4v*)(out + i) = o;
}

// -------- simple transpose + convert: out[C][R] = in[R][C] (small weights) ----
__global__ void transpose_k(const void* __restrict__ in, bf16* __restrict__ out,
                            int R, int C, const int* __restrict__ flag) {
  size_t idx = (size_t)blockIdx.x * 256 + threadIdx.x;
  if (idx >= (size_t)R * C) return;
  int fl = *flag;
  int c = (int)(idx / R);
  int r = (int)(idx % R);
  size_t src = (size_t)r * C + c;
  bf16 v = fl ? ((const bf16*)in)[src] : __float2bfloat16(((const float*)in)[src]);
  out[(size_t)c * R + r] = v;
}

// -------- tiled transpose + convert (R,C multiples of 64) ----
__global__ __launch_bounds__(256) void transpose_tile_k(
    const void* __restrict__ in, bf16* __restrict__ out, int R, int C,
    const int* __restrict__ flag) {
  __shared__ bf16 t[64][65];
  int c0 = blockIdx.x * 64, r0 = blockIdx.y * 64;
  int fl = *flag;
  int ci = threadIdx.x & 63, grp = threadIdx.x >> 6;
#pragma unroll
  for (int rr = grp; rr < 64; rr += 4) {
    size_t src = (size_t)(r0 + rr) * C + c0 + ci;
    t[rr][ci] = fl ? ((const bf16*)in)[src]
                   : __float2bfloat16(((const float*)in)[src]);
  }
  __syncthreads();
#pragma unroll
  for (int cc = grp; cc < 64; cc += 4) {
    out[(size_t)(c0 + cc) * R + r0 + ci] = t[ci][cc];
  }
}

// ---------------- rmsnorm: per-row over 1024 ----------------
__global__ __launch_bounds__(256) void rmsnorm_k(const bf16* __restrict__ x,
                                                 const bf16* __restrict__ w,
                                                 bf16* __restrict__ xn) {
  int row = blockIdx.x;
  const bf16* xp = x + (size_t)row * DMODEL;
  int tid = threadIdx.x;
  short4v raw = *(const short4v*)(xp + tid * 4);
  float f[4];
#pragma unroll
  for (int k = 0; k < 4; k++) f[k] = bits2f((unsigned short)raw[k]);
  float s = f[0] * f[0] + f[1] * f[1] + f[2] * f[2] + f[3] * f[3];
#pragma unroll
  for (int o = 32; o > 0; o >>= 1) s += __shfl_down(s, o);
  __shared__ float ps[4];
  __shared__ float stot;
  if ((tid & 63) == 0) ps[tid >> 6] = s;
  __syncthreads();
  if (tid == 0) stot = ps[0] + ps[1] + ps[2] + ps[3];
  __syncthreads();
  float scale = 1.0f / sqrtf(stot * (1.0f / DMODEL) + 1e-5f);
  short4v wr = *(const short4v*)(w + tid * 4);
  short4v o;
#pragma unroll
  for (int k = 0; k < 4; k++)
    o[k] = f2bits(f[k] * scale * bits2f((unsigned short)wr[k]));
  *(short4v*)(xn + (size_t)row * DMODEL + tid * 4) = o;
}

// ---------------- GEMM: C[M,N] = A[M,K] @ Bt[N,K]^T ----------------
// m97 structure: 128x128 tile, BK=32, global_load_lds width-16 staging,
// unpadded LDS 128x32. EPI: 0 = bf16; 1 = f32 + dt slice bf16 (n<64);
// 2 = softplus(v+b[n]) f32; 3 = v + x, bf16/f32 per *flag.
template <int EPI>
__global__ __launch_bounds__(256, 2) void gemm_bt(
    const bf16* __restrict__ A, const bf16* __restrict__ Bt, void* __restrict__ Cout,
    int M, int N, int K, const bf16* __restrict__ eb, const bf16* __restrict__ ex,
    bf16* __restrict__ dtb, const int* __restrict__ flag) {
  __shared__ bf16 As[128 * 32];
  __shared__ bf16 Bs[128 * 32];
  int tid = threadIdx.x;
  int lane = tid & 63;
  int wave = tid >> 6;
  int wm = (wave >> 1) * 64, wn = (wave & 1) * 64;
  int m0 = blockIdx.y * 128, n0 = blockIdx.x * 128;

  floatx4 acc[4][4] = {};

  int sr = tid >> 2;          // staging row 0..63
  int sc = (tid & 3) * 8;     // staging k-col
  int bn0 = n0 + sr;        if (bn0 > N - 1) bn0 = N - 1;
  int bn1 = n0 + sr + 64;   if (bn1 > N - 1) bn1 = N - 1;
  // wave-uniform LDS bases (wave covers rows wave*16..wave*16+15)
  bf16* asb = As + wave * 16 * 32;
  bf16* bsb = Bs + wave * 16 * 32;

  const bf16* a0p = A + (size_t)(m0 + sr) * K + sc;
  const bf16* a1p = A + (size_t)(m0 + sr + 64) * K + sc;
  const bf16* b0p = Bt + (size_t)bn0 * K + sc;
  const bf16* b1p = Bt + (size_t)bn1 * K + sc;

  for (int k0 = 0; k0 < K; k0 += 32) {
    __syncthreads();   // prev ds_reads done before overwrite
    gl_lds16(a0p + k0, asb);
    gl_lds16(a1p + k0, asb + 64 * 32);
    gl_lds16(b0p + k0, bsb);
    gl_lds16(b1p + k0, bsb + 64 * 32);
    __syncthreads();   // compiler emits vmcnt(0) drain here

    int fr = lane & 15;
    int q = lane >> 4;
    short8 af[4], bfr[4];
#pragma unroll
    for (int i = 0; i < 4; i++) {
      af[i] = *(const short8*)(As + (wm + i * 16 + fr) * 32 + q * 8);
      bfr[i] = *(const short8*)(Bs + (wn + i * 16 + fr) * 32 + q * 8);
    }
#pragma unroll
    for (int i = 0; i < 4; i++)
#pragma unroll
      for (int j = 0; j < 4; j++)
        acc[i][j] =
            __builtin_amdgcn_mfma_f32_16x16x32_bf16(af[i], bfr[j], acc[i][j], 0, 0, 0);
  }

  int fl = (EPI == 3) ? *flag : 0;
  // epilogue: C/D layout col=lane&15, row=(lane>>4)*4+reg  [m89-verified]
  int cr = (lane >> 4) * 4;
  int cc = lane & 15;
#pragma unroll
  for (int i = 0; i < 4; i++) {
#pragma unroll
    for (int j = 0; j < 4; j++) {
      int n = n0 + wn + j * 16 + cc;
      if (n >= N) continue;
#pragma unroll
      for (int r = 0; r < 4; r++) {
        int m = m0 + wm + i * 16 + cr + r;
        float v = acc[i][j][r];
        size_t o = (size_t)m * N + n;
        if (EPI == 0) {
          ((bf16*)Cout)[o] = __float2bfloat16(v);
        } else if (EPI == 1) {
          ((float*)Cout)[o] = v;
          if (n < DTRANK) dtb[(size_t)m * DTRANK + n] = __float2bfloat16(v);
        } else if (EPI == 2) {
          float t = v + (float)eb[n];
          ((float*)Cout)[o] = (t > 20.f) ? t : log1pf(__expf(t));
        } else {
          float v2 = v + (float)ex[o];
          if (fl) ((bf16*)Cout)[o] = __float2bfloat16(v2);
          else    ((float*)Cout)[o] = v2;
        }
      }
    }
  }
}

// ---------------- causal depthwise conv (k=4) + bias + silu ----------------
__global__ __launch_bounds__(256) void conv_silu_k(const bf16* __restrict__ xr,
                                                   const bf16* __restrict__ cw,
                                                   const bf16* __restrict__ cb,
                                                   bf16* __restrict__ u) {
  size_t idx = (size_t)blockIdx.x * 256 + threadIdx.x;
  int d = (int)(idx & (DINNER - 1));
  size_t m = idx >> 11;
  int t = (int)(m & (NT - 1));
  float acc = (float)cb[d];
#pragma unroll
  for (int j = 0; j < 4; j++) {
    int tt = t - 3 + j;
    if (tt >= 0)
      acc += (float)cw[d * 4 + j] * (float)xr[(m - 3 + j) * GG + d];
  }
  float s = acc / (1.f + __expf(-acc));
  u[idx] = __float2bfloat16(s);
}

// ===================== chunked parallel scan =====================
// scan1/scan3 layout: block 256 thr; d = dblk*128 + (tid>>1); half (tid&1)
// holds states n0=half*8 .. +7.  grid = NB*NC*16.
// chunkP/S/H layout: [b][chunk][d][n] f32.

// pass 1: local scan h=0; emit S (local final h) and P = exp(Av * sum(delta))
__global__ __launch_bounds__(256) void scan1_k(
    const float* __restrict__ delta, const bf16* __restrict__ u,
    const float* __restrict__ xdbc, const bf16* __restrict__ A_log,
    float* __restrict__ chunkP, float* __restrict__ chunkS) {
  int tid = threadIdx.x;
  int bc = blockIdx.x;
  int dblk = bc & 15;
  int chunk = (bc >> 4) & (NC - 1);
  int b = bc >> 9;
  int d = (dblk << 7) + (tid >> 1);
  int n0 = (tid & 1) * 8;
  float Av[8], h[8] = {};
#pragma unroll
  for (int k = 0; k < 8; k++) Av[k] = -__expf((float)A_log[d * DSTATE + n0 + k]);
  size_t base = (size_t)b * NT + (size_t)chunk * CL;

  float sd = 0.f;
  float dl = delta[base * DINNER + d];
  float uu = (float)u[base * DINNER + d];
  floatx4 B0 = *(const floatx4*)(xdbc + base * 96 + 64 + n0);
  floatx4 B1 = *(const floatx4*)(xdbc + base * 96 + 68 + n0);

  for (int t = 0; t < CL; t++) {
    size_t m2 = base + (t + 1 < CL ? t + 1 : CL - 1);
    float dl_n = delta[m2 * DINNER + d];
    float uu_n = (float)u[m2 * DINNER + d];
    floatx4 B0n = *(const floatx4*)(xdbc + m2 * 96 + 64 + n0);
    floatx4 B1n = *(const floatx4*)(xdbc + m2 * 96 + 68 + n0);
    float du = dl * uu;
    sd += dl;
#pragma unroll
    for (int k = 0; k < 4; k++) {
      float dA = __expf(dl * Av[k]);
      h[k] = fmaf(dA, h[k], du * B0[k]);
    }
#pragma unroll
    for (int k = 0; k < 4; k++) {
      float dA = __expf(dl * Av[4 + k]);
      h[4 + k] = fmaf(dA, h[4 + k], du * B1[k]);
    }
    dl = dl_n; uu = uu_n; B0 = B0n; B1 = B1n;
  }
  size_t o = (((size_t)b * NC + chunk) * DINNER + d) * DSTATE + n0;
  floatx4 P0, P1, S0, S1;
#pragma unroll
  for (int k = 0; k < 4; k++) {
    P0[k] = __expf(Av[k] * sd);
    P1[k] = __expf(Av[4 + k] * sd);
    S0[k] = h[k];
    S1[k] = h[4 + k];
  }
  *(floatx4*)(chunkP + o) = P0;
  *(floatx4*)(chunkP + o + 4) = P1;
  *(floatx4*)(chunkS + o) = S0;
  *(floatx4*)(chunkS + o + 4) = S1;
}

// pass 2: sequential over chunks: emit carry-in H_c; H_{c+1} = P_c H_c + S_c
__global__ __launch_bounds__(256) void scan2_k(
    const float* __restrict__ chunkP, const float* __restrict__ chunkS,
    float* __restrict__ chunkH) {
  int tid = threadIdx.x;
  int bc = blockIdx.x;
  int dblk = bc & 31;
  int b = bc >> 5;
  int d = (dblk << 6) + (tid >> 2);
  int n0 = (tid & 3) * 4;
  floatx4 h = {};
  size_t o0 = ((size_t)b * NC * DINNER + d) * DSTATE + n0;
  floatx4 P = *(const floatx4*)(chunkP + o0);
  floatx4 S = *(const floatx4*)(chunkS + o0);
  for (int c = 0; c < NC; c++) {
    floatx4 Pn = {}, Sn = {};
    if (c + 1 < NC) {
      size_t o = o0 + (size_t)(c + 1) * DINNER * DSTATE;
      Pn = *(const floatx4*)(chunkP + o);
      Sn = *(const floatx4*)(chunkS + o);
    }
    size_t o = o0 + (size_t)c * DINNER * DSTATE;
    *(floatx4*)(chunkH + o) = h;
#pragma unroll
    for (int k = 0; k < 4; k++) h[k] = fmaf(P[k], h[k], S[k]);
    P = Pn; S = Sn;
  }
}

// pass 3: replay chunk from carry-in H, produce gated y
__global__ __launch_bounds__(256) void scan3_k(
    const float* __restrict__ delta, const bf16* __restrict__ u,
    const float* __restrict__ xdbc, const bf16* __restrict__ xr,
    const bf16* __restrict__ A_log, const bf16* __restrict__ Dp,
    const float* __restrict__ chunkH, bf16* __restrict__ y) {
  int tid = threadIdx.x;
  int bc = blockIdx.x;
  int dblk = bc & 15;
  int chunk = (bc >> 4) & (NC - 1);
  int b = bc >> 9;
  int d = (dblk << 7) + (tid >> 1);
  int n0 = (tid & 1) * 8;
  float Av[8], h[8];
#pragma unroll
  for (int k = 0; k < 8; k++) Av[k] = -__expf((float)A_log[d * DSTATE + n0 + k]);
  {
    size_t o = (((size_t)b * NC + chunk) * DINNER + d) * DSTATE + n0;
    floatx4 H0 = *(const floatx4*)(chunkH + o);
    floatx4 H1 = *(const floatx4*)(chunkH + o + 4);
#pragma unroll
    for (int k = 0; k < 4; k++) { h[k] = H0[k]; h[4 + k] = H1[k]; }
  }
  float Dd = (float)Dp[d];
  size_t base = (size_t)b * NT + (size_t)chunk * CL;

  float dl = delta[base * DINNER + d];
  float uu = (float)u[base * DINNER + d];
  floatx4 B0 = *(const floatx4*)(xdbc + base * 96 + 64 + n0);
  floatx4 B1 = *(const floatx4*)(xdbc + base * 96 + 68 + n0);
  floatx4 C0 = *(const floatx4*)(xdbc + base * 96 + 80 + n0);
  floatx4 C1 = *(const floatx4*)(xdbc + base * 96 + 84 + n0);
  float rs = (float)xr[base * GG + DINNER + d];

  for (int t = 0; t < CL; t++) {
    size_t m2 = base + (t + 1 < CL ? t + 1 : CL - 1);
    float dl_n = delta[m2 * DINNER + d];
    float uu_n = (float)u[m2 * DINNER + d];
    floatx4 B0n = *(const floatx4*)(xdbc + m2 * 96 + 64 + n0);
    floatx4 B1n = *(const floatx4*)(xdbc + m2 * 96 + 68 + n0);
    floatx4 C0n = *(const floatx4*)(xdbc + m2 * 96 + 80 + n0);
    floatx4 C1n = *(const floatx4*)(xdbc + m2 * 96 + 84 + n0);
    float rs_n = (float)xr[m2 * GG + DINNER + d];
    float du = dl * uu;
    float ys = 0.f;
#pragma unroll
    for (int k = 0; k < 4; k++) {
      float dA = __expf(dl * Av[k]);
      h[k] = fmaf(dA, h[k], du * B0[k]);
      ys = fmaf(h[k], C0[k], ys);
    }
#pragma unroll
    for (int k = 0; k < 4; k++) {
      float dA = __expf(dl * Av[4 + k]);
      h[4 + k] = fmaf(dA, h[4 + k], du * B1[k]);
      ys = fmaf(h[4 + k], C1[k], ys);
    }
    ys += __shfl_xor(ys, 1);
    if ((tid & 1) == 0) {
      size_t mm = base + t;
      float sig = 1.f / (1.f + __expf(-rs));
      y[mm * DINNER + d] = __float2bfloat16((ys + uu * Dd) * (rs * sig));
    }
    dl = dl_n; uu = uu_n; B0 = B0n; B1 = B1n; C0 = C0n; C1 = C1n; rs = rs_n;
  }
}

// ---------------- launch ----------------
extern "C" void kernel_launch(void* const* d_in, const int* in_sizes, int n_in,
                              void* d_out, int out_size, void* d_ws, size_t ws_size,
                              hipStream_t stream) {
  const void* x_raw = d_in[0];
  const void* norm_w_raw = d_in[1];
  const void* w_in_raw = d_in[2];
  const void* conv_w_raw = d_in[3];
  const void* conv_b_raw = d_in[4];
  const void* w_x_raw = d_in[5];
  const void* w_dt_raw = d_in[6];
  const void* b_dt_raw = d_in[7];
  const void* A_log_raw = d_in[8];
  const void* Dp_raw = d_in[9];
  const void* w_out_raw = d_in[10];

  char* ws = (char*)d_ws;
  size_t off = 0;
  auto alloc = [&](size_t bytes) {
    size_t o = off;
    off += (bytes + 255) & ~(size_t)255;
    return o;
  };
  int* flag = (int*)(ws + alloc(256));
  bf16* xb = (bf16*)(ws + alloc((size_t)NM * DMODEL * 2));
  bf16* nwb = (bf16*)(ws + alloc((size_t)DMODEL * 2));
  bf16* cwb = (bf16*)(ws + alloc((size_t)DINNER * 4 * 2));
  bf16* cbb = (bf16*)(ws + alloc((size_t)DINNER * 2));
  bf16* bdtb = (bf16*)(ws + alloc((size_t)DINNER * 2));
  bf16* alogb = (bf16*)(ws + alloc((size_t)DINNER * DSTATE * 2));
  bf16* Db = (bf16*)(ws + alloc((size_t)DINNER * 2));
  bf16* xn = (bf16*)(ws + alloc((size_t)NM * DMODEL * 2));
  bf16* xr = (bf16*)(ws + alloc((size_t)NM * GG * 2));
  bf16* u = (bf16*)(ws + alloc((size_t)NM * DINNER * 2));
  float* xdbc = (float*)(ws + alloc((size_t)NM * 96 * 4));
  bf16* dtb = (bf16*)(ws + alloc((size_t)NM * 64 * 2));
  float* delta = (float*)(ws + alloc((size_t)NM * DINNER * 4));
  bf16* yb = (bf16*)(ws + alloc((size_t)NM * DINNER * 2));
  bf16* w_inT = (bf16*)(ws + alloc((size_t)DMODEL * GG * 2));
  bf16* w_xT = (bf16*)(ws + alloc((size_t)DINNER * 96 * 2));
  bf16* w_dtT = (bf16*)(ws + alloc((size_t)DTRANK * DINNER * 2));
  bf16* w_outT = (bf16*)(ws + alloc((size_t)DINNER * DMODEL * 2));

  // Chunk buffers ALIAS dead regions (no net workspace growth):
  //   xn    (16 MiB, dead after gemm<0>) -> chunkP | chunkS
  //   w_inT ( 8 MiB, dead after gemm<0>) -> chunkH
  float* chunkP = (float*)xn;
  float* chunkS = (float*)((char*)xn + (size_t)NB * NC * DINNER * DSTATE * 4);
  float* chunkH = (float*)w_inT;

  detect_k<<<1, 64, 0, stream>>>((const unsigned*)A_log_raw, flag);

  convert_k<<<(NM * DMODEL / 4 + 255) / 256, 256, 0, stream>>>(x_raw, xb, NM * DMODEL, flag);
  convert_k<<<(DMODEL / 4 + 255) / 256, 256, 0, stream>>>(norm_w_raw, nwb, DMODEL, flag);
  convert_k<<<(DINNER + 255) / 256, 256, 0, stream>>>(conv_w_raw, cwb, DINNER * 4, flag);
  convert_k<<<(DINNER / 4 + 255) / 256, 256, 0, stream>>>(conv_b_raw, cbb, DINNER, flag);
  convert_k<<<(DINNER / 4 + 255) / 256, 256, 0, stream>>>(b_dt_raw, bdtb, DINNER, flag);
  convert_k<<<(DINNER * DSTATE / 4 + 255) / 256, 256, 0, stream>>>(A_log_raw, alogb, DINNER * DSTATE, flag);
  convert_k<<<(DINNER / 4 + 255) / 256, 256, 0, stream>>>(Dp_raw, Db, DINNER, flag);

  // weight transposes to [N][K] k-contiguous bf16
  transpose_tile_k<<<dim3(GG / 64, DMODEL / 64), 256, 0, stream>>>(w_in_raw, w_inT, DMODEL, GG, flag);
  transpose_k<<<(DINNER * 96 + 255) / 256, 256, 0, stream>>>(w_x_raw, w_xT, DINNER, 96, flag);
  transpose_tile_k<<<dim3(DINNER / 64, DTRANK / 64), 256, 0, stream>>>(w_dt_raw, w_dtT, DTRANK, DINNER, flag);
  transpose_tile_k<<<dim3(DMODEL / 64, DINNER / 64), 256, 0, stream>>>(w_out_raw, w_outT, DINNER, DMODEL, flag);

  rmsnorm_k<<<NM, 256, 0, stream>>>(xb, nwb, xn);

  // xr = xn @ w_in   (M=8192, N=4096, K=1024)
  gemm_bt<0><<<dim3(GG / 128, NM / 128), 256, 0, stream>>>(
      xn, w_inT, xr, NM, GG, DMODEL, nullptr, nullptr, nullptr, flag);
  // xn, w_inT dead from here (aliased by chunkP/S/H)
  conv_silu_k<<<(size_t)NM * DINNER / 256, 256, 0, stream>>>(xr, cwb, cbb, u);

  // xdbc = u @ w_x (N=96) + fused dt slice -> dtb
  gemm_bt<1><<<dim3(1, NM / 128), 256, 0, stream>>>(
      u, w_xT, xdbc, NM, 96, DINNER, nullptr, nullptr, dtb, flag);

  // delta = softplus(dt @ w_dt + b_dt)  (M=8192, N=2048, K=64)
  gemm_bt<2><<<dim3(DINNER / 128, NM / 128), 256, 0, stream>>>(
      dtb, w_dtT, delta, NM, DINNER, DTRANK, bdtb, nullptr, nullptr, flag);

  // chunked parallel scan
  scan1_k<<<NB * NC * 16, 256, 0, stream>>>(delta, u, xdbc, alogb, chunkP, chunkS);
  scan2_k<<<NB * 32, 256, 0, stream>>>(chunkP, chunkS, chunkH);
  scan3_k<<<NB * NC * 16, 256, 0, stream>>>(delta, u, xdbc, xr, alogb, Db, chunkH, yb);

  // out = x + yb @ w_out  (M=8192, N=1024, K=2048)
  gemm_bt<3><<<dim3(DMODEL / 128, NM / 128), 256, 0, stream>>>(
      yb, w_outT, d_out, NM, DMODEL, DINNER, nullptr, xb, nullptr, flag);
}